// Round 5
// 631.395 us; speedup vs baseline: 1.1036x; 1.1036x over previous
//
#include <hip/hip_runtime.h>
#include <cstdint>
#include <cstddef>

// B=2, S=2048, D=1024, H=16, HD=64. Inputs fp32, output fp32.
// R18: bisect. R13-VERBATIM pipeline (VALU Q/K GEMM w/ fused RoPE, attn fp32-ctx,
// VALU out GEMM) with ONE substitution: V projection via new MFMA path
// (cvt_x -> trans_w -> gemm_v_mfma, 128x128 tile BK=32, 32KB LDS, reg-staged,
// two-pass V^T epilogue reusing staging LDS).
// ws (bytes, 40MiB = R13-proven): Qb[0,8.4M) Kb[8.4,16.8M) Vt[16.8,25.2M)
//   ctx fp32 [25.2,41.9M); Xb (bf16) and WvT overlay [25.2,35.7M), dead before attn.
#define BB 2
#define SS 2048
#define DD 1024
#define HH 16
#define HDD 64

typedef unsigned short u16;
typedef unsigned int u32;
typedef __attribute__((ext_vector_type(8))) short bf16x8;
typedef __attribute__((ext_vector_type(4))) float f32x4;

__device__ __forceinline__ u16 f2bf(float f) {
    union { float f; u32 u; } c; c.f = f;
    u32 r = c.u + 0x7fffu + ((c.u >> 16) & 1u);  // RNE
    return (u16)(r >> 16);
}

// ---------------- prep: X fp32 -> bf16 (NEW, under test) -------------------------------
__global__ __launch_bounds__(256) void cvt_x(const float* __restrict__ X, u16* __restrict__ Xb)
{
    const int idx0 = blockIdx.x * 256 + threadIdx.x;
    #pragma unroll
    for (int i = 0; i < 4; i++) {
        const int c = idx0 + i * 262144;
        const float4 v = *(const float4*)&X[(size_t)c * 4];
        ushort4 o;
        o.x = f2bf(v.x); o.y = f2bf(v.y); o.z = f2bf(v.z); o.w = f2bf(v.w);
        *(ushort4*)&Xb[(size_t)c * 4] = o;
    }
}

// ---------------- prep: W[k][n] fp32 -> W^T[n][k] bf16 (NEW, under test) ---------------
__global__ __launch_bounds__(256) void trans_w(
    const float* __restrict__ W, u16* __restrict__ WT)
{
    __shared__ float L[32][33];
    const int k0 = blockIdx.x * 32, n0 = blockIdx.y * 32;
    const int tx = threadIdx.x & 31, ty = threadIdx.x >> 5;
    #pragma unroll
    for (int i = 0; i < 4; i++)
        L[ty + 8 * i][tx] = W[(size_t)(k0 + ty + 8 * i) * DD + n0 + tx];
    __syncthreads();
    #pragma unroll
    for (int i = 0; i < 4; i++) {
        const int n = ty + 8 * i;
        WT[(size_t)(n0 + n) * DD + k0 + tx] = f2bf(L[tx][n]);
    }
}

// ---------------- V GEMM via MFMA (NEW, under test): Xb @ WvT -> V^T bf16 --------------
// 128x128 tile, BK=32, 4 waves 64x64, reg-staged dbuf LDS (32KB total).
// Epilogue: two passes (m-halves) through Ts[128][64] fp32 reusing sm.
__global__ __launch_bounds__(256) void gemm_v_mfma(
    const u16* __restrict__ Xb, const u16* __restrict__ WvT, u16* __restrict__ outT)
{
    __shared__ __align__(16) u16 sm[16384];   // 32KB: 2 bufs x (A 8KB + B 8KB)
    const int tid = threadIdx.x;
    const int lane = tid & 63;
    const int w = tid >> 6;
    const int li = lane & 15, quad = lane >> 4;
    const int wr = w >> 1, wc = w & 1;
    const int n0 = blockIdx.x * 128;
    const int m0 = blockIdx.y * 128;

    const int srow = tid >> 2;          // 0..63
    const int scol = (tid & 3) * 8;     // 0,8,16,24

    uint4 ra[2], rb[2], na[2], nb[2];
    #pragma unroll
    for (int rr = 0; rr < 2; rr++) {
        ra[rr] = *(const uint4*)(Xb  + (size_t)(m0 + rr * 64 + srow) * DD + scol);
        rb[rr] = *(const uint4*)(WvT + (size_t)(n0 + rr * 64 + srow) * DD + scol);
    }

    f32x4 acc[4][4] = {};
    for (int t = 0; t < 32; t++) {
        u16* base = sm + (t & 1) * 8192;
        #pragma unroll
        for (int rr = 0; rr < 2; rr++) {
            *(uint4*)&base[(rr * 64 + srow) * 32 + scol] = ra[rr];
            *(uint4*)&base[4096 + (rr * 64 + srow) * 32 + scol] = rb[rr];
        }
        if (t < 31) {
            const int k1 = (t + 1) * 32;
            #pragma unroll
            for (int rr = 0; rr < 2; rr++) {
                na[rr] = *(const uint4*)(Xb  + (size_t)(m0 + rr * 64 + srow) * DD + k1 + scol);
                nb[rr] = *(const uint4*)(WvT + (size_t)(n0 + rr * 64 + srow) * DD + k1 + scol);
            }
        }
        __syncthreads();
        bf16x8 a[4], b[4];
        #pragma unroll
        for (int f = 0; f < 4; f++) {
            a[f] = *(const bf16x8*)(base + (wr * 64 + f * 16 + li) * 32 + quad * 8);
            b[f] = *(const bf16x8*)(base + 4096 + (wc * 64 + f * 16 + li) * 32 + quad * 8);
        }
        #pragma unroll
        for (int fm = 0; fm < 4; fm++)
            #pragma unroll
            for (int fn = 0; fn < 4; fn++)
                acc[fm][fn] = __builtin_amdgcn_mfma_f32_16x16x32_bf16(
                    a[fm], b[fn], acc[fm][fn], 0, 0, 0);
        if (t < 31) {
            #pragma unroll
            for (int rr = 0; rr < 2; rr++) { ra[rr] = na[rr]; rb[rr] = nb[rr]; }
        }
        __syncthreads();
    }

    // V^T epilogue: Ts[n_local][m_in_half] fp32 (32KB), two m-halves.
    float (*Ts)[64] = (float(*)[64])sm;
    const int bidx = m0 >> 11;
    const int s0 = m0 & (SS - 1);
    #pragma unroll
    for (int p = 0; p < 2; p++) {
        __syncthreads();
        if (wr == p) {
            #pragma unroll
            for (int fm = 0; fm < 4; fm++)
                #pragma unroll
                for (int fn = 0; fn < 4; fn++)
                    *(float4*)&Ts[wc * 64 + fn * 16 + li][fm * 16 + quad * 4] =
                        make_float4(acc[fm][fn][0], acc[fm][fn][1],
                                    acc[fm][fn][2], acc[fm][fn][3]);
        }
        __syncthreads();
        #pragma unroll
        for (int i = 0; i < 4; i++) {
            const int c = tid + 256 * i;     // 0..1023
            const int nr = c >> 3;           // 0..127
            const int mc = c & 7;            // 0..7
            const int n = n0 + nr;
            const int h = n >> 6, hd = n & 63;
            const float4 v0 = *(const float4*)&Ts[nr][mc * 8];
            const float4 v1 = *(const float4*)&Ts[nr][mc * 8 + 4];
            uint4 ov;
            ov.x = (u32)f2bf(v0.x) | ((u32)f2bf(v0.y) << 16);
            ov.y = (u32)f2bf(v0.z) | ((u32)f2bf(v0.w) << 16);
            ov.z = (u32)f2bf(v1.x) | ((u32)f2bf(v1.y) << 16);
            ov.w = (u32)f2bf(v1.z) | ((u32)f2bf(v1.w) << 16);
            *(uint4*)&outT[((size_t)(bidx * HH + h) * HDD + hd) * SS + s0 + p * 64 + mc * 8] = ov;
        }
    }
}

// ---------------- Q/K projection GEMM (R13 VERBATIM): fp32 VALU + fused RoPE -----------
__global__ __launch_bounds__(256) void gemm_qk_bf16(
    const float* __restrict__ X, const float* __restrict__ W,
    u16* __restrict__ out, const float scale)
{
    __shared__ float As[32][68];
    __shared__ float Bs[32][68];
    const int tid = threadIdx.x;
    const int m0 = blockIdx.y * 64;
    const int n0 = blockIdx.x * 64;
    const int tm = tid >> 4, tn = tid & 15;
    const int alr = tid >> 2;
    const int alc = (tid & 3) * 8;
    const int bkr = tid >> 3;
    const int bnc = (tid & 7) * 8;
    float acc[4][4] = {};

    for (int k0 = 0; k0 < DD; k0 += 32) {
        const float4 a0 = *(const float4*)&X[(size_t)(m0 + alr) * DD + k0 + alc];
        const float4 a1 = *(const float4*)&X[(size_t)(m0 + alr) * DD + k0 + alc + 4];
        const float4 b0 = *(const float4*)&W[(size_t)(k0 + bkr) * DD + n0 + bnc];
        const float4 b1 = *(const float4*)&W[(size_t)(k0 + bkr) * DD + n0 + bnc + 4];
        __syncthreads();
        As[alc + 0][alr] = a0.x; As[alc + 1][alr] = a0.y;
        As[alc + 2][alr] = a0.z; As[alc + 3][alr] = a0.w;
        As[alc + 4][alr] = a1.x; As[alc + 5][alr] = a1.y;
        As[alc + 6][alr] = a1.z; As[alc + 7][alr] = a1.w;
        Bs[bkr][bnc + 0] = b0.x; Bs[bkr][bnc + 1] = b0.y;
        Bs[bkr][bnc + 2] = b0.z; Bs[bkr][bnc + 3] = b0.w;
        Bs[bkr][bnc + 4] = b1.x; Bs[bkr][bnc + 5] = b1.y;
        Bs[bkr][bnc + 6] = b1.z; Bs[bkr][bnc + 7] = b1.w;
        __syncthreads();
        #pragma unroll
        for (int kk = 0; kk < 32; kk++) {
            const float4 a4 = *(const float4*)&As[kk][tm * 4];
            const float4 b4 = *(const float4*)&Bs[kk][tn * 4];
            const float ar[4] = {a4.x, a4.y, a4.z, a4.w};
            const float br[4] = {b4.x, b4.y, b4.z, b4.w};
            #pragma unroll
            for (int i = 0; i < 4; i++)
                #pragma unroll
                for (int j = 0; j < 4; j++)
                    acc[i][j] = fmaf(ar[i], br[j], acc[i][j]);
        }
    }

    const int h = blockIdx.x;
    const int hd0 = tn * 4;
    #pragma unroll
    for (int r = 0; r < 4; r++) {
        const int m = m0 + tm * 4 + r;
        const int b = m >> 11;
        const int srow = m & (SS - 1);
        float v0 = acc[r][0], v1 = acc[r][1], v2 = acc[r][2], v3 = acc[r][3];
        {   // interleaved RoPE
            const float fs = (float)srow;
            const float inv0 = exp2f((float)(hd0 >> 1) * -0.4152410118609203f);
            const float inv1 = exp2f((float)((hd0 >> 1) + 1) * -0.4152410118609203f);
            float sn0, cs0, sn1, cs1;
            sincosf(fs * inv0, &sn0, &cs0);
            sincosf(fs * inv1, &sn1, &cs1);
            const float r0 = v0 * cs0 - v1 * sn0;
            const float r1 = v0 * sn0 + v1 * cs0;
            const float r2 = v2 * cs1 - v3 * sn1;
            const float r3 = v2 * sn1 + v3 * cs1;
            v0 = r0; v1 = r1; v2 = r2; v3 = r3;
        }
        ushort4 o;
        o.x = f2bf(v0 * scale); o.y = f2bf(v1 * scale);
        o.z = f2bf(v2 * scale); o.w = f2bf(v3 * scale);
        *(ushort4*)&out[((size_t)(b * HH + h) * SS + srow) * HDD + hd0] = o;
    }
}

// ---------------- MFMA flash attention (R13 VERBATIM, fp32 ctx out) --------------------
__global__ __launch_bounds__(256) void attn_mfma(
    const u16* __restrict__ Qb, const u16* __restrict__ Kb,
    const u16* __restrict__ Vt, float* __restrict__ ctx)
{
    __shared__ u16 Ks[64][72];      // [key][d]
    __shared__ u16 Vs[64][72];      // [d][key]  (from V^T)
    __shared__ u16 Ps[4][16][72];   // per-wave [q][key]
    const int tid = threadIdx.x;
    const int lane = tid & 63;
    const int w = tid >> 6;
    const int li = lane & 15;
    const int quad = lane >> 4;
    const int bh = blockIdx.y;
    const int q0 = (gridDim.x - 1 - blockIdx.x) * 64;   // heavy blocks first

    bf16x8 aQ0, aQ1;
    {
        const u16* qg = Qb + ((size_t)bh * SS + q0 + 16 * w + li) * HDD + quad * 8;
        aQ0 = *(const bf16x8*)qg;
        aQ1 = *(const bf16x8*)(qg + 32);
    }

    f32x4 O[4] = {};
    float m_r[4] = {-1e30f, -1e30f, -1e30f, -1e30f};
    float l_r[4] = {};

    const int ntiles = (q0 >> 6) + 1;
    const int krow = tid >> 3;
    const int kch = (tid & 7) * 8;

    for (int jt = 0; jt < ntiles; jt++) {
        const int j0 = jt << 6;
        const uint4 k0v = *(const uint4*)(Kb + ((size_t)bh * SS + j0 + krow) * HDD + kch);
        const uint4 k1v = *(const uint4*)(Kb + ((size_t)bh * SS + j0 + 32 + krow) * HDD + kch);
        const uint4 v0v = *(const uint4*)(Vt + ((size_t)bh * HDD + krow) * SS + j0 + kch);
        const uint4 v1v = *(const uint4*)(Vt + ((size_t)bh * HDD + 32 + krow) * SS + j0 + kch);
        __syncthreads();
        *(uint4*)&Ks[krow][kch] = k0v;
        *(uint4*)&Ks[32 + krow][kch] = k1v;
        *(uint4*)&Vs[krow][kch] = v0v;
        *(uint4*)&Vs[32 + krow][kch] = v1v;
        __syncthreads();

        f32x4 S[4];
        #pragma unroll
        for (int t = 0; t < 4; t++) {
            const bf16x8 b0 = *(const bf16x8*)&Ks[16 * t + li][quad * 8];
            const bf16x8 b1 = *(const bf16x8*)&Ks[16 * t + li][32 + quad * 8];
            f32x4 acc = {};
            acc = __builtin_amdgcn_mfma_f32_16x16x32_bf16(aQ0, b0, acc, 0, 0, 0);
            acc = __builtin_amdgcn_mfma_f32_16x16x32_bf16(aQ1, b1, acc, 0, 0, 0);
            S[t] = acc;
        }

        if (jt == ntiles - 1) {
            #pragma unroll
            for (int t = 0; t < 4; t++)
                #pragma unroll
                for (int r = 0; r < 4; r++)
                    if (16 * t + li > 16 * w + quad * 4 + r) S[t][r] = -1e30f;
        }

        float p[4][4];
        #pragma unroll
        for (int r = 0; r < 4; r++) {
            float mt = fmaxf(fmaxf(S[0][r], S[1][r]), fmaxf(S[2][r], S[3][r]));
            #pragma unroll
            for (int off = 1; off < 16; off <<= 1)
                mt = fmaxf(mt, __shfl_xor(mt, off));
            const float mnew = fmaxf(m_r[r], mt);
            const float alpha = __expf(m_r[r] - mnew);
            float ls = 0.f;
            #pragma unroll
            for (int t = 0; t < 4; t++) {
                p[r][t] = __expf(S[t][r] - mnew);
                ls += p[r][t];
            }
            #pragma unroll
            for (int off = 1; off < 16; off <<= 1)
                ls += __shfl_xor(ls, off);
            l_r[r] = l_r[r] * alpha + ls;
            m_r[r] = mnew;
            #pragma unroll
            for (int t2 = 0; t2 < 4; t2++) O[t2][r] *= alpha;
        }

        #pragma unroll
        for (int r = 0; r < 4; r++)
            #pragma unroll
            for (int t = 0; t < 4; t++)
                Ps[w][quad * 4 + r][16 * t + li] = f2bf(p[r][t]);

        const bf16x8 aP0 = *(const bf16x8*)&Ps[w][li][quad * 8];
        const bf16x8 aP1 = *(const bf16x8*)&Ps[w][li][32 + quad * 8];
        #pragma unroll
        for (int t2 = 0; t2 < 4; t2++) {
            const bf16x8 b0 = *(const bf16x8*)&Vs[16 * t2 + li][quad * 8];
            const bf16x8 b1 = *(const bf16x8*)&Vs[16 * t2 + li][32 + quad * 8];
            O[t2] = __builtin_amdgcn_mfma_f32_16x16x32_bf16(aP0, b0, O[t2], 0, 0, 0);
            O[t2] = __builtin_amdgcn_mfma_f32_16x16x32_bf16(aP1, b1, O[t2], 0, 0, 0);
        }
    }

    const int b = bh >> 4, h = bh & 15;
    #pragma unroll
    for (int r = 0; r < 4; r++) {
        const float inv = 1.f / l_r[r];
        const int row = q0 + 16 * w + quad * 4 + r;
        #pragma unroll
        for (int t2 = 0; t2 < 4; t2++)
            ctx[((size_t)b * SS + row) * DD + h * HDD + 16 * t2 + li] = O[t2][r] * inv;
    }
}

// ---------------- Output projection (R13 VERBATIM): ctx(fp32) @ Wo(fp32) ---------------
__global__ __launch_bounds__(256) void gemm_out(
    const float* __restrict__ Xf, const float* __restrict__ W, float* __restrict__ out)
{
    __shared__ float As[32][68];
    __shared__ float Bs[32][68];
    const int tid = threadIdx.x;
    const int m0 = blockIdx.y * 64;
    const int n0 = blockIdx.x * 64;
    const int tm = tid >> 4, tn = tid & 15;
    const int alr = tid >> 2;
    const int alc = (tid & 3) * 8;
    const int bkr = tid >> 3;
    const int bnc = (tid & 7) * 8;
    float acc[4][4] = {};

    for (int k0 = 0; k0 < DD; k0 += 32) {
        const float4 a0 = *(const float4*)&Xf[(size_t)(m0 + alr) * DD + k0 + alc];
        const float4 a1 = *(const float4*)&Xf[(size_t)(m0 + alr) * DD + k0 + alc + 4];
        const float4 b0 = *(const float4*)&W[(size_t)(k0 + bkr) * DD + n0 + bnc];
        const float4 b1 = *(const float4*)&W[(size_t)(k0 + bkr) * DD + n0 + bnc + 4];
        __syncthreads();
        As[alc + 0][alr] = a0.x; As[alc + 1][alr] = a0.y;
        As[alc + 2][alr] = a0.z; As[alc + 3][alr] = a0.w;
        As[alc + 4][alr] = a1.x; As[alc + 5][alr] = a1.y;
        As[alc + 6][alr] = a1.z; As[alc + 7][alr] = a1.w;
        Bs[bkr][bnc + 0] = b0.x; Bs[bkr][bnc + 1] = b0.y;
        Bs[bkr][bnc + 2] = b0.z; Bs[bkr][bnc + 3] = b0.w;
        Bs[bkr][bnc + 4] = b1.x; Bs[bkr][bnc + 5] = b1.y;
        Bs[bkr][bnc + 6] = b1.z; Bs[bkr][bnc + 7] = b1.w;
        __syncthreads();
        #pragma unroll
        for (int kk = 0; kk < 32; kk++) {
            const float4 a4 = *(const float4*)&As[kk][tm * 4];
            const float4 b4 = *(const float4*)&Bs[kk][tn * 4];
            const float ar[4] = {a4.x, a4.y, a4.z, a4.w};
            const float br[4] = {b4.x, b4.y, b4.z, b4.w};
            #pragma unroll
            for (int i = 0; i < 4; i++)
                #pragma unroll
                for (int j = 0; j < 4; j++)
                    acc[i][j] = fmaf(ar[i], br[j], acc[i][j]);
        }
    }

    #pragma unroll
    for (int r = 0; r < 4; r++) {
        const int m = m0 + tm * 4 + r;
        *(float4*)&out[(size_t)m * DD + n0 + tn * 4] =
            make_float4(acc[r][0], acc[r][1], acc[r][2], acc[r][3]);
    }
}

extern "C" void kernel_launch(void* const* d_in, const int* in_sizes, int n_in,
                              void* d_out, int out_size, void* d_ws, size_t ws_size,
                              hipStream_t stream) {
    const float* x  = (const float*)d_in[0];
    const float* Wq = (const float*)d_in[1];
    const float* Wk = (const float*)d_in[2];
    const float* Wv = (const float*)d_in[3];
    const float* Wo = (const float*)d_in[4];
    float* out = (float*)d_out;

    u16* ws16 = (u16*)d_ws;
    const size_t E = 4194304;                 // B*H*S*HD elems
    u16* Qb   = ws16;                         // [0, E)
    u16* Kb   = ws16 + E;                     // [E, 2E)
    u16* Vt   = ws16 + 2 * E;                 // [2E, 3E)
    float* ctxf = (float*)(ws16 + 3 * E);     // fp32, 16 MiB (R13 layout, 40 MiB total)
    u16* Xb   = ws16 + 3 * E;                 // overlay in ctx region, dead before attn
    u16* WvT  = ws16 + 4 * E;                 // overlay in ctx region, dead before attn

    hipLaunchKernelGGL(cvt_x, dim3(1024), dim3(256), 0, stream, x, Xb);
    hipLaunchKernelGGL(trans_w, dim3(32, 32), dim3(256), 0, stream, Wv, WvT);
    dim3 gg(DD / 64, (BB * SS) / 64), bb(256);
    hipLaunchKernelGGL(gemm_qk_bf16, gg, bb, 0, stream, x, Wq, Qb, 0.125f);
    hipLaunchKernelGGL(gemm_qk_bf16, gg, bb, 0, stream, x, Wk, Kb, 1.0f);
    hipLaunchKernelGGL(gemm_v_mfma, dim3(8, 32), dim3(256), 0, stream, Xb, WvT, Vt);
    hipLaunchKernelGGL(attn_mfma, dim3(SS / 64, BB * HH), dim3(256), 0, stream,
                       Qb, Kb, Vt, ctxf);
    hipLaunchKernelGGL(gemm_out, gg, bb, 0, stream, ctxf, Wo, out);
}

// Round 6
// 538.377 us; speedup vs baseline: 1.2942x; 1.1728x over previous
//
#include <hip/hip_runtime.h>
#include <cstdint>
#include <cstddef>

// B=2, S=2048, D=1024, H=16, HD=64. Inputs fp32, output fp32.
// R19: Q/K moved onto the R18-VERIFIED MFMA core (BK=32, 32KB LDS, reg-staged dbuf,
// 128x128 tile, 4 waves 64x64). Only new code: mode-0 RoPE epilogue in the same
// two-pass 32KB pattern as the verified V^T epilogue. V path, attn, out GEMM, preps
// are R18-verbatim.
// ws (40MiB proven): Qb[0,8M) Kb[8,16M) Vt[16,24M) ctx fp32 [24,40M);
//   overlays (dead before attn): Xb[24,32M) WqT[32,34M) WkT[34,36M) WvT[36,38M).
#define BB 2
#define SS 2048
#define DD 1024
#define HH 16
#define HDD 64

typedef unsigned short u16;
typedef unsigned int u32;
typedef __attribute__((ext_vector_type(8))) short bf16x8;
typedef __attribute__((ext_vector_type(4))) float f32x4;

__device__ __forceinline__ u16 f2bf(float f) {
    union { float f; u32 u; } c; c.f = f;
    u32 r = c.u + 0x7fffu + ((c.u >> 16) & 1u);  // RNE
    return (u16)(r >> 16);
}

// ---------------- prep: X fp32 -> bf16 (verified R18) ----------------------------------
__global__ __launch_bounds__(256) void cvt_x(const float* __restrict__ X, u16* __restrict__ Xb)
{
    const int idx0 = blockIdx.x * 256 + threadIdx.x;
    #pragma unroll
    for (int i = 0; i < 4; i++) {
        const int c = idx0 + i * 262144;
        const float4 v = *(const float4*)&X[(size_t)c * 4];
        ushort4 o;
        o.x = f2bf(v.x); o.y = f2bf(v.y); o.z = f2bf(v.z); o.w = f2bf(v.w);
        *(ushort4*)&Xb[(size_t)c * 4] = o;
    }
}

// ---------------- prep: W[k][n] fp32 -> W^T[n][k] bf16 (verified R18) ------------------
__global__ __launch_bounds__(256) void trans_w(
    const float* __restrict__ W, u16* __restrict__ WT)
{
    __shared__ float L[32][33];
    const int k0 = blockIdx.x * 32, n0 = blockIdx.y * 32;
    const int tx = threadIdx.x & 31, ty = threadIdx.x >> 5;
    #pragma unroll
    for (int i = 0; i < 4; i++)
        L[ty + 8 * i][tx] = W[(size_t)(k0 + ty + 8 * i) * DD + n0 + tx];
    __syncthreads();
    #pragma unroll
    for (int i = 0; i < 4; i++) {
        const int n = ty + 8 * i;
        WT[(size_t)(n0 + n) * DD + k0 + tx] = f2bf(L[tx][n]);
    }
}

// ---------------- Q/K GEMM via verified MFMA core + RoPE epilogue (mode-0, NEW) --------
__global__ __launch_bounds__(256) void gemm_qk_mfma(
    const u16* __restrict__ Xb, const u16* __restrict__ WT, u16* __restrict__ outp,
    const float scale)
{
    __shared__ __align__(16) u16 sm[16384];   // 32KB: 2 bufs x (A 8KB + B 8KB)
    const int tid = threadIdx.x;
    const int lane = tid & 63;
    const int w = tid >> 6;
    const int li = lane & 15, quad = lane >> 4;
    const int wr = w >> 1, wc = w & 1;
    const int n0 = blockIdx.x * 128;
    const int m0 = blockIdx.y * 128;

    const int srow = tid >> 2;          // 0..63
    const int scol = (tid & 3) * 8;     // 0,8,16,24

    uint4 ra[2], rb[2], na[2], nb[2];
    #pragma unroll
    for (int rr = 0; rr < 2; rr++) {
        ra[rr] = *(const uint4*)(Xb + (size_t)(m0 + rr * 64 + srow) * DD + scol);
        rb[rr] = *(const uint4*)(WT + (size_t)(n0 + rr * 64 + srow) * DD + scol);
    }

    f32x4 acc[4][4] = {};
    for (int t = 0; t < 32; t++) {
        u16* base = sm + (t & 1) * 8192;
        #pragma unroll
        for (int rr = 0; rr < 2; rr++) {
            *(uint4*)&base[(rr * 64 + srow) * 32 + scol] = ra[rr];
            *(uint4*)&base[4096 + (rr * 64 + srow) * 32 + scol] = rb[rr];
        }
        if (t < 31) {
            const int k1 = (t + 1) * 32;
            #pragma unroll
            for (int rr = 0; rr < 2; rr++) {
                na[rr] = *(const uint4*)(Xb + (size_t)(m0 + rr * 64 + srow) * DD + k1 + scol);
                nb[rr] = *(const uint4*)(WT + (size_t)(n0 + rr * 64 + srow) * DD + k1 + scol);
            }
        }
        __syncthreads();
        bf16x8 a[4], b[4];
        #pragma unroll
        for (int f = 0; f < 4; f++) {
            a[f] = *(const bf16x8*)(base + (wr * 64 + f * 16 + li) * 32 + quad * 8);
            b[f] = *(const bf16x8*)(base + 4096 + (wc * 64 + f * 16 + li) * 32 + quad * 8);
        }
        #pragma unroll
        for (int fm = 0; fm < 4; fm++)
            #pragma unroll
            for (int fn = 0; fn < 4; fn++)
                acc[fm][fn] = __builtin_amdgcn_mfma_f32_16x16x32_bf16(
                    a[fm], b[fn], acc[fm][fn], 0, 0, 0);
        if (t < 31) {
            #pragma unroll
            for (int rr = 0; rr < 2; rr++) { ra[rr] = na[rr]; rb[rr] = nb[rr]; }
        }
        __syncthreads();
    }

    // mode-0 epilogue: two m-half passes through Ts[64][128] fp32 (32KB), RoPE+scale.
    float (*Ts)[128] = (float(*)[128])sm;
    const int bidx = m0 >> 11;
    const int s0 = m0 & (SS - 1);
    #pragma unroll
    for (int p = 0; p < 2; p++) {
        __syncthreads();
        if (wr == p) {
            #pragma unroll
            for (int fm = 0; fm < 4; fm++)
                #pragma unroll
                for (int fn = 0; fn < 4; fn++)
                    #pragma unroll
                    for (int r = 0; r < 4; r++)
                        Ts[fm * 16 + quad * 4 + r][wc * 64 + fn * 16 + li] = acc[fm][fn][r];
        }
        __syncthreads();
        #pragma unroll
        for (int i = 0; i < 4; i++) {
            const int c = tid + 256 * i;     // 0..1023
            const int mr = c >> 4;           // 0..63
            const int nc = c & 15;           // 0..15
            const int s = s0 + p * 64 + mr;
            const int n = n0 + nc * 8;
            const int h = n >> 6, hd0 = n & 63;
            const float4 v0 = *(const float4*)&Ts[mr][nc * 8];
            const float4 v1 = *(const float4*)&Ts[mr][nc * 8 + 4];
            const float fs = (float)s;
            u32 w0, w1, w2, w3;
            {
                const float inv = exp2f((float)((hd0 >> 1) + 0) * -0.4152410118609203f);
                float sn, cs; sincosf(fs * inv, &sn, &cs);
                w0 = (u32)f2bf((v0.x * cs - v0.y * sn) * scale) |
                     ((u32)f2bf((v0.x * sn + v0.y * cs) * scale) << 16);
            }
            {
                const float inv = exp2f((float)((hd0 >> 1) + 1) * -0.4152410118609203f);
                float sn, cs; sincosf(fs * inv, &sn, &cs);
                w1 = (u32)f2bf((v0.z * cs - v0.w * sn) * scale) |
                     ((u32)f2bf((v0.z * sn + v0.w * cs) * scale) << 16);
            }
            {
                const float inv = exp2f((float)((hd0 >> 1) + 2) * -0.4152410118609203f);
                float sn, cs; sincosf(fs * inv, &sn, &cs);
                w2 = (u32)f2bf((v1.x * cs - v1.y * sn) * scale) |
                     ((u32)f2bf((v1.x * sn + v1.y * cs) * scale) << 16);
            }
            {
                const float inv = exp2f((float)((hd0 >> 1) + 3) * -0.4152410118609203f);
                float sn, cs; sincosf(fs * inv, &sn, &cs);
                w3 = (u32)f2bf((v1.z * cs - v1.w * sn) * scale) |
                     ((u32)f2bf((v1.z * sn + v1.w * cs) * scale) << 16);
            }
            uint4 ov; ov.x = w0; ov.y = w1; ov.z = w2; ov.w = w3;
            *(uint4*)&outp[((size_t)(bidx * HH + h) * SS + s) * HDD + hd0] = ov;
        }
    }
}

// ---------------- V GEMM via MFMA (R18 VERBATIM, verified) -----------------------------
__global__ __launch_bounds__(256) void gemm_v_mfma(
    const u16* __restrict__ Xb, const u16* __restrict__ WvT, u16* __restrict__ outT)
{
    __shared__ __align__(16) u16 sm[16384];   // 32KB
    const int tid = threadIdx.x;
    const int lane = tid & 63;
    const int w = tid >> 6;
    const int li = lane & 15, quad = lane >> 4;
    const int wr = w >> 1, wc = w & 1;
    const int n0 = blockIdx.x * 128;
    const int m0 = blockIdx.y * 128;

    const int srow = tid >> 2;          // 0..63
    const int scol = (tid & 3) * 8;     // 0,8,16,24

    uint4 ra[2], rb[2], na[2], nb[2];
    #pragma unroll
    for (int rr = 0; rr < 2; rr++) {
        ra[rr] = *(const uint4*)(Xb  + (size_t)(m0 + rr * 64 + srow) * DD + scol);
        rb[rr] = *(const uint4*)(WvT + (size_t)(n0 + rr * 64 + srow) * DD + scol);
    }

    f32x4 acc[4][4] = {};
    for (int t = 0; t < 32; t++) {
        u16* base = sm + (t & 1) * 8192;
        #pragma unroll
        for (int rr = 0; rr < 2; rr++) {
            *(uint4*)&base[(rr * 64 + srow) * 32 + scol] = ra[rr];
            *(uint4*)&base[4096 + (rr * 64 + srow) * 32 + scol] = rb[rr];
        }
        if (t < 31) {
            const int k1 = (t + 1) * 32;
            #pragma unroll
            for (int rr = 0; rr < 2; rr++) {
                na[rr] = *(const uint4*)(Xb  + (size_t)(m0 + rr * 64 + srow) * DD + k1 + scol);
                nb[rr] = *(const uint4*)(WvT + (size_t)(n0 + rr * 64 + srow) * DD + k1 + scol);
            }
        }
        __syncthreads();
        bf16x8 a[4], b[4];
        #pragma unroll
        for (int f = 0; f < 4; f++) {
            a[f] = *(const bf16x8*)(base + (wr * 64 + f * 16 + li) * 32 + quad * 8);
            b[f] = *(const bf16x8*)(base + 4096 + (wc * 64 + f * 16 + li) * 32 + quad * 8);
        }
        #pragma unroll
        for (int fm = 0; fm < 4; fm++)
            #pragma unroll
            for (int fn = 0; fn < 4; fn++)
                acc[fm][fn] = __builtin_amdgcn_mfma_f32_16x16x32_bf16(
                    a[fm], b[fn], acc[fm][fn], 0, 0, 0);
        if (t < 31) {
            #pragma unroll
            for (int rr = 0; rr < 2; rr++) { ra[rr] = na[rr]; rb[rr] = nb[rr]; }
        }
        __syncthreads();
    }

    float (*Ts)[64] = (float(*)[64])sm;
    const int bidx = m0 >> 11;
    const int s0 = m0 & (SS - 1);
    #pragma unroll
    for (int p = 0; p < 2; p++) {
        __syncthreads();
        if (wr == p) {
            #pragma unroll
            for (int fm = 0; fm < 4; fm++)
                #pragma unroll
                for (int fn = 0; fn < 4; fn++)
                    *(float4*)&Ts[wc * 64 + fn * 16 + li][fm * 16 + quad * 4] =
                        make_float4(acc[fm][fn][0], acc[fm][fn][1],
                                    acc[fm][fn][2], acc[fm][fn][3]);
        }
        __syncthreads();
        #pragma unroll
        for (int i = 0; i < 4; i++) {
            const int c = tid + 256 * i;     // 0..1023
            const int nr = c >> 3;           // 0..127
            const int mc = c & 7;            // 0..7
            const int n = n0 + nr;
            const int h = n >> 6, hd = n & 63;
            const float4 v0 = *(const float4*)&Ts[nr][mc * 8];
            const float4 v1 = *(const float4*)&Ts[nr][mc * 8 + 4];
            uint4 ov;
            ov.x = (u32)f2bf(v0.x) | ((u32)f2bf(v0.y) << 16);
            ov.y = (u32)f2bf(v0.z) | ((u32)f2bf(v0.w) << 16);
            ov.z = (u32)f2bf(v1.x) | ((u32)f2bf(v1.y) << 16);
            ov.w = (u32)f2bf(v1.z) | ((u32)f2bf(v1.w) << 16);
            *(uint4*)&outT[((size_t)(bidx * HH + h) * HDD + hd) * SS + s0 + p * 64 + mc * 8] = ov;
        }
    }
}

// ---------------- MFMA flash attention (R13 VERBATIM, fp32 ctx out) --------------------
__global__ __launch_bounds__(256) void attn_mfma(
    const u16* __restrict__ Qb, const u16* __restrict__ Kb,
    const u16* __restrict__ Vt, float* __restrict__ ctx)
{
    __shared__ u16 Ks[64][72];      // [key][d]
    __shared__ u16 Vs[64][72];      // [d][key]  (from V^T)
    __shared__ u16 Ps[4][16][72];   // per-wave [q][key]
    const int tid = threadIdx.x;
    const int lane = tid & 63;
    const int w = tid >> 6;
    const int li = lane & 15;
    const int quad = lane >> 4;
    const int bh = blockIdx.y;
    const int q0 = (gridDim.x - 1 - blockIdx.x) * 64;   // heavy blocks first

    bf16x8 aQ0, aQ1;
    {
        const u16* qg = Qb + ((size_t)bh * SS + q0 + 16 * w + li) * HDD + quad * 8;
        aQ0 = *(const bf16x8*)qg;
        aQ1 = *(const bf16x8*)(qg + 32);
    }

    f32x4 O[4] = {};
    float m_r[4] = {-1e30f, -1e30f, -1e30f, -1e30f};
    float l_r[4] = {};

    const int ntiles = (q0 >> 6) + 1;
    const int krow = tid >> 3;
    const int kch = (tid & 7) * 8;

    for (int jt = 0; jt < ntiles; jt++) {
        const int j0 = jt << 6;
        const uint4 k0v = *(const uint4*)(Kb + ((size_t)bh * SS + j0 + krow) * HDD + kch);
        const uint4 k1v = *(const uint4*)(Kb + ((size_t)bh * SS + j0 + 32 + krow) * HDD + kch);
        const uint4 v0v = *(const uint4*)(Vt + ((size_t)bh * HDD + krow) * SS + j0 + kch);
        const uint4 v1v = *(const uint4*)(Vt + ((size_t)bh * HDD + 32 + krow) * SS + j0 + kch);
        __syncthreads();
        *(uint4*)&Ks[krow][kch] = k0v;
        *(uint4*)&Ks[32 + krow][kch] = k1v;
        *(uint4*)&Vs[krow][kch] = v0v;
        *(uint4*)&Vs[32 + krow][kch] = v1v;
        __syncthreads();

        f32x4 S[4];
        #pragma unroll
        for (int t = 0; t < 4; t++) {
            const bf16x8 b0 = *(const bf16x8*)&Ks[16 * t + li][quad * 8];
            const bf16x8 b1 = *(const bf16x8*)&Ks[16 * t + li][32 + quad * 8];
            f32x4 acc = {};
            acc = __builtin_amdgcn_mfma_f32_16x16x32_bf16(aQ0, b0, acc, 0, 0, 0);
            acc = __builtin_amdgcn_mfma_f32_16x16x32_bf16(aQ1, b1, acc, 0, 0, 0);
            S[t] = acc;
        }

        if (jt == ntiles - 1) {
            #pragma unroll
            for (int t = 0; t < 4; t++)
                #pragma unroll
                for (int r = 0; r < 4; r++)
                    if (16 * t + li > 16 * w + quad * 4 + r) S[t][r] = -1e30f;
        }

        float p[4][4];
        #pragma unroll
        for (int r = 0; r < 4; r++) {
            float mt = fmaxf(fmaxf(S[0][r], S[1][r]), fmaxf(S[2][r], S[3][r]));
            #pragma unroll
            for (int off = 1; off < 16; off <<= 1)
                mt = fmaxf(mt, __shfl_xor(mt, off));
            const float mnew = fmaxf(m_r[r], mt);
            const float alpha = __expf(m_r[r] - mnew);
            float ls = 0.f;
            #pragma unroll
            for (int t = 0; t < 4; t++) {
                p[r][t] = __expf(S[t][r] - mnew);
                ls += p[r][t];
            }
            #pragma unroll
            for (int off = 1; off < 16; off <<= 1)
                ls += __shfl_xor(ls, off);
            l_r[r] = l_r[r] * alpha + ls;
            m_r[r] = mnew;
            #pragma unroll
            for (int t2 = 0; t2 < 4; t2++) O[t2][r] *= alpha;
        }

        #pragma unroll
        for (int r = 0; r < 4; r++)
            #pragma unroll
            for (int t = 0; t < 4; t++)
                Ps[w][quad * 4 + r][16 * t + li] = f2bf(p[r][t]);

        const bf16x8 aP0 = *(const bf16x8*)&Ps[w][li][quad * 8];
        const bf16x8 aP1 = *(const bf16x8*)&Ps[w][li][32 + quad * 8];
        #pragma unroll
        for (int t2 = 0; t2 < 4; t2++) {
            const bf16x8 b0 = *(const bf16x8*)&Vs[16 * t2 + li][quad * 8];
            const bf16x8 b1 = *(const bf16x8*)&Vs[16 * t2 + li][32 + quad * 8];
            O[t2] = __builtin_amdgcn_mfma_f32_16x16x32_bf16(aP0, b0, O[t2], 0, 0, 0);
            O[t2] = __builtin_amdgcn_mfma_f32_16x16x32_bf16(aP1, b1, O[t2], 0, 0, 0);
        }
    }

    const int b = bh >> 4, h = bh & 15;
    #pragma unroll
    for (int r = 0; r < 4; r++) {
        const float inv = 1.f / l_r[r];
        const int row = q0 + 16 * w + quad * 4 + r;
        #pragma unroll
        for (int t2 = 0; t2 < 4; t2++)
            ctx[((size_t)b * SS + row) * DD + h * HDD + 16 * t2 + li] = O[t2][r] * inv;
    }
}

// ---------------- Output projection (R13 VERBATIM): ctx(fp32) @ Wo(fp32) ---------------
__global__ __launch_bounds__(256) void gemm_out(
    const float* __restrict__ Xf, const float* __restrict__ W, float* __restrict__ out)
{
    __shared__ float As[32][68];
    __shared__ float Bs[32][68];
    const int tid = threadIdx.x;
    const int m0 = blockIdx.y * 64;
    const int n0 = blockIdx.x * 64;
    const int tm = tid >> 4, tn = tid & 15;
    const int alr = tid >> 2;
    const int alc = (tid & 3) * 8;
    const int bkr = tid >> 3;
    const int bnc = (tid & 7) * 8;
    float acc[4][4] = {};

    for (int k0 = 0; k0 < DD; k0 += 32) {
        const float4 a0 = *(const float4*)&Xf[(size_t)(m0 + alr) * DD + k0 + alc];
        const float4 a1 = *(const float4*)&Xf[(size_t)(m0 + alr) * DD + k0 + alc + 4];
        const float4 b0 = *(const float4*)&W[(size_t)(k0 + bkr) * DD + n0 + bnc];
        const float4 b1 = *(const float4*)&W[(size_t)(k0 + bkr) * DD + n0 + bnc + 4];
        __syncthreads();
        As[alc + 0][alr] = a0.x; As[alc + 1][alr] = a0.y;
        As[alc + 2][alr] = a0.z; As[alc + 3][alr] = a0.w;
        As[alc + 4][alr] = a1.x; As[alc + 5][alr] = a1.y;
        As[alc + 6][alr] = a1.z; As[alc + 7][alr] = a1.w;
        Bs[bkr][bnc + 0] = b0.x; Bs[bkr][bnc + 1] = b0.y;
        Bs[bkr][bnc + 2] = b0.z; Bs[bkr][bnc + 3] = b0.w;
        Bs[bkr][bnc + 4] = b1.x; Bs[bkr][bnc + 5] = b1.y;
        Bs[bkr][bnc + 6] = b1.z; Bs[bkr][bnc + 7] = b1.w;
        __syncthreads();
        #pragma unroll
        for (int kk = 0; kk < 32; kk++) {
            const float4 a4 = *(const float4*)&As[kk][tm * 4];
            const float4 b4 = *(const float4*)&Bs[kk][tn * 4];
            const float ar[4] = {a4.x, a4.y, a4.z, a4.w};
            const float br[4] = {b4.x, b4.y, b4.z, b4.w};
            #pragma unroll
            for (int i = 0; i < 4; i++)
                #pragma unroll
                for (int j = 0; j < 4; j++)
                    acc[i][j] = fmaf(ar[i], br[j], acc[i][j]);
        }
    }

    #pragma unroll
    for (int r = 0; r < 4; r++) {
        const int m = m0 + tm * 4 + r;
        *(float4*)&out[(size_t)m * DD + n0 + tn * 4] =
            make_float4(acc[r][0], acc[r][1], acc[r][2], acc[r][3]);
    }
}

extern "C" void kernel_launch(void* const* d_in, const int* in_sizes, int n_in,
                              void* d_out, int out_size, void* d_ws, size_t ws_size,
                              hipStream_t stream) {
    const float* x  = (const float*)d_in[0];
    const float* Wq = (const float*)d_in[1];
    const float* Wk = (const float*)d_in[2];
    const float* Wv = (const float*)d_in[3];
    const float* Wo = (const float*)d_in[4];
    float* out = (float*)d_out;

    u16* ws16 = (u16*)d_ws;
    const size_t E = 4194304;                 // B*H*S*HD elems
    const size_t M = 1048576;                 // D*D elems
    u16* Qb   = ws16;                         // [0, E)
    u16* Kb   = ws16 + E;                     // [E, 2E)
    u16* Vt   = ws16 + 2 * E;                 // [2E, 3E)
    float* ctxf = (float*)(ws16 + 3 * E);     // fp32, 16 MiB (40 MiB total, proven)
    u16* Xb   = ws16 + 3 * E;                 // overlay in ctx region, dead before attn
    u16* WqT  = ws16 + 4 * E;                 // overlay, dead before attn
    u16* WkT  = WqT + M;                      // overlay, dead before attn
    u16* WvT  = WkT + M;                      // overlay, dead before attn

    hipLaunchKernelGGL(cvt_x, dim3(1024), dim3(256), 0, stream, x, Xb);
    hipLaunchKernelGGL(trans_w, dim3(32, 32), dim3(256), 0, stream, Wq, WqT);
    hipLaunchKernelGGL(trans_w, dim3(32, 32), dim3(256), 0, stream, Wk, WkT);
    hipLaunchKernelGGL(trans_w, dim3(32, 32), dim3(256), 0, stream, Wv, WvT);
    hipLaunchKernelGGL(gemm_qk_mfma, dim3(8, 32), dim3(256), 0, stream, Xb, WqT, Qb, 0.125f);
    hipLaunchKernelGGL(gemm_qk_mfma, dim3(8, 32), dim3(256), 0, stream, Xb, WkT, Kb, 1.0f);
    hipLaunchKernelGGL(gemm_v_mfma, dim3(8, 32), dim3(256), 0, stream, Xb, WvT, Vt);
    hipLaunchKernelGGL(attn_mfma, dim3(SS / 64, BB * HH), dim3(256), 0, stream,
                       Qb, Kb, Vt, ctxf);
    hipLaunchKernelGGL(gemm_out, dim3(DD / 64, (BB * SS) / 64), dim3(256), 0, stream,
                       ctxf, Wo, out);
}

// Round 7
// 476.616 us; speedup vs baseline: 1.4619x; 1.1296x over previous
//
#include <hip/hip_runtime.h>
#include <cstdint>
#include <cstddef>

// B=2, S=2048, D=1024, H=16, HD=64. Inputs fp32, output fp32.
// R20: (1) QKV fused into ONE launch (768 blocks = 3/CU) -- outputs & weights are
// contiguous so pointer select is pure arithmetic on single bases (no multi-restrict
// select). Core + both epilogues R19-VERBATIM (verified). (2) Output GEMM on the
// verified MFMA core, single bf16 product (error budget ~2e-3 << 0.03125 threshold):
// attn writes ctx bf16; direct fp32 epilogue in the verified C-layout convention.
// ws (40MiB proven): QKV[0,24M) = Qb|Kb|Vt contiguous; Xb[24,32M)->ctxb bf16;
//   WTall[32,38M) = WqT|WkT|WvT contiguous; WoT[38,40M).
#define BB 2
#define SS 2048
#define DD 1024
#define HH 16
#define HDD 64

typedef unsigned short u16;
typedef unsigned int u32;
typedef __attribute__((ext_vector_type(8))) short bf16x8;
typedef __attribute__((ext_vector_type(4))) float f32x4;

__device__ __forceinline__ u16 f2bf(float f) {
    union { float f; u32 u; } c; c.f = f;
    u32 r = c.u + 0x7fffu + ((c.u >> 16) & 1u);  // RNE
    return (u16)(r >> 16);
}

// ---------------- prep: X fp32 -> bf16 (verified) --------------------------------------
__global__ __launch_bounds__(256) void cvt_x(const float* __restrict__ X, u16* __restrict__ Xb)
{
    const int idx0 = blockIdx.x * 256 + threadIdx.x;
    #pragma unroll
    for (int i = 0; i < 4; i++) {
        const int c = idx0 + i * 262144;
        const float4 v = *(const float4*)&X[(size_t)c * 4];
        ushort4 o;
        o.x = f2bf(v.x); o.y = f2bf(v.y); o.z = f2bf(v.z); o.w = f2bf(v.w);
        *(ushort4*)&Xb[(size_t)c * 4] = o;
    }
}

// ---------------- prep: W[k][n] fp32 -> W^T[n][k] bf16 (verified) ----------------------
__global__ __launch_bounds__(256) void trans_w(
    const float* __restrict__ W, u16* __restrict__ WT)
{
    __shared__ float L[32][33];
    const int k0 = blockIdx.x * 32, n0 = blockIdx.y * 32;
    const int tx = threadIdx.x & 31, ty = threadIdx.x >> 5;
    #pragma unroll
    for (int i = 0; i < 4; i++)
        L[ty + 8 * i][tx] = W[(size_t)(k0 + ty + 8 * i) * DD + n0 + tx];
    __syncthreads();
    #pragma unroll
    for (int i = 0; i < 4; i++) {
        const int n = ty + 8 * i;
        WT[(size_t)(n0 + n) * DD + k0 + tx] = f2bf(L[tx][n]);
    }
}

// ---------------- fused QKV GEMM on the verified MFMA core -----------------------------
// grid (24, 32): which = bx>>3 in {Q,K,V}; n0 = (bx&7)*128; m0 = by*128.
// BT / outp selected by pointer ARITHMETIC on single contiguous bases.
__global__ __launch_bounds__(256) void gemm_qkv_all(
    const u16* __restrict__ Xb, const u16* __restrict__ WTall, u16* __restrict__ QKVb)
{
    __shared__ __align__(16) u16 sm[16384];   // 32KB: 2 bufs x (A 8KB + B 8KB)
    const int tid = threadIdx.x;
    const int lane = tid & 63;
    const int w = tid >> 6;
    const int li = lane & 15, quad = lane >> 4;
    const int wr = w >> 1, wc = w & 1;
    const int which = blockIdx.x >> 3;
    const int n0 = (blockIdx.x & 7) * 128;
    const int m0 = blockIdx.y * 128;
    const u16* BT = WTall + (size_t)which * (DD * DD);
    u16* outp = QKVb + (size_t)which * ((size_t)BB * HH * SS * HDD);
    const float scale = (which == 0) ? 0.125f : 1.0f;

    const int srow = tid >> 2;          // 0..63
    const int scol = (tid & 3) * 8;     // 0,8,16,24

    uint4 ra[2], rb[2], na[2], nb[2];
    #pragma unroll
    for (int rr = 0; rr < 2; rr++) {
        ra[rr] = *(const uint4*)(Xb + (size_t)(m0 + rr * 64 + srow) * DD + scol);
        rb[rr] = *(const uint4*)(BT + (size_t)(n0 + rr * 64 + srow) * DD + scol);
    }

    f32x4 acc[4][4] = {};
    for (int t = 0; t < 32; t++) {
        u16* base = sm + (t & 1) * 8192;
        #pragma unroll
        for (int rr = 0; rr < 2; rr++) {
            *(uint4*)&base[(rr * 64 + srow) * 32 + scol] = ra[rr];
            *(uint4*)&base[4096 + (rr * 64 + srow) * 32 + scol] = rb[rr];
        }
        if (t < 31) {
            const int k1 = (t + 1) * 32;
            #pragma unroll
            for (int rr = 0; rr < 2; rr++) {
                na[rr] = *(const uint4*)(Xb + (size_t)(m0 + rr * 64 + srow) * DD + k1 + scol);
                nb[rr] = *(const uint4*)(BT + (size_t)(n0 + rr * 64 + srow) * DD + k1 + scol);
            }
        }
        __syncthreads();
        bf16x8 a[4], b[4];
        #pragma unroll
        for (int f = 0; f < 4; f++) {
            a[f] = *(const bf16x8*)(base + (wr * 64 + f * 16 + li) * 32 + quad * 8);
            b[f] = *(const bf16x8*)(base + 4096 + (wc * 64 + f * 16 + li) * 32 + quad * 8);
        }
        #pragma unroll
        for (int fm = 0; fm < 4; fm++)
            #pragma unroll
            for (int fn = 0; fn < 4; fn++)
                acc[fm][fn] = __builtin_amdgcn_mfma_f32_16x16x32_bf16(
                    a[fm], b[fn], acc[fm][fn], 0, 0, 0);
        if (t < 31) {
            #pragma unroll
            for (int rr = 0; rr < 2; rr++) { ra[rr] = na[rr]; rb[rr] = nb[rr]; }
        }
        __syncthreads();
    }

    const int bidx = m0 >> 11;
    const int s0 = m0 & (SS - 1);
    if (which < 2) {
        // RoPE epilogue (R19-verified): two m-half passes through Ts[64][128] fp32.
        float (*Ts)[128] = (float(*)[128])sm;
        #pragma unroll
        for (int p = 0; p < 2; p++) {
            __syncthreads();
            if (wr == p) {
                #pragma unroll
                for (int fm = 0; fm < 4; fm++)
                    #pragma unroll
                    for (int fn = 0; fn < 4; fn++)
                        #pragma unroll
                        for (int r = 0; r < 4; r++)
                            Ts[fm * 16 + quad * 4 + r][wc * 64 + fn * 16 + li] = acc[fm][fn][r];
            }
            __syncthreads();
            #pragma unroll
            for (int i = 0; i < 4; i++) {
                const int c = tid + 256 * i;     // 0..1023
                const int mr = c >> 4;           // 0..63
                const int nc = c & 15;           // 0..15
                const int s = s0 + p * 64 + mr;
                const int n = n0 + nc * 8;
                const int h = n >> 6, hd0 = n & 63;
                const float4 v0 = *(const float4*)&Ts[mr][nc * 8];
                const float4 v1 = *(const float4*)&Ts[mr][nc * 8 + 4];
                const float fs = (float)s;
                u32 w0, w1, w2, w3;
                {
                    const float inv = exp2f((float)((hd0 >> 1) + 0) * -0.4152410118609203f);
                    float sn, cs; sincosf(fs * inv, &sn, &cs);
                    w0 = (u32)f2bf((v0.x * cs - v0.y * sn) * scale) |
                         ((u32)f2bf((v0.x * sn + v0.y * cs) * scale) << 16);
                }
                {
                    const float inv = exp2f((float)((hd0 >> 1) + 1) * -0.4152410118609203f);
                    float sn, cs; sincosf(fs * inv, &sn, &cs);
                    w1 = (u32)f2bf((v0.z * cs - v0.w * sn) * scale) |
                         ((u32)f2bf((v0.z * sn + v0.w * cs) * scale) << 16);
                }
                {
                    const float inv = exp2f((float)((hd0 >> 1) + 2) * -0.4152410118609203f);
                    float sn, cs; sincosf(fs * inv, &sn, &cs);
                    w2 = (u32)f2bf((v1.x * cs - v1.y * sn) * scale) |
                         ((u32)f2bf((v1.x * sn + v1.y * cs) * scale) << 16);
                }
                {
                    const float inv = exp2f((float)((hd0 >> 1) + 3) * -0.4152410118609203f);
                    float sn, cs; sincosf(fs * inv, &sn, &cs);
                    w3 = (u32)f2bf((v1.z * cs - v1.w * sn) * scale) |
                         ((u32)f2bf((v1.z * sn + v1.w * cs) * scale) << 16);
                }
                uint4 ov; ov.x = w0; ov.y = w1; ov.z = w2; ov.w = w3;
                *(uint4*)&outp[((size_t)(bidx * HH + h) * SS + s) * HDD + hd0] = ov;
            }
        }
    } else {
        // V^T epilogue (R18-verified): two m-half passes through Ts[128][64] fp32.
        float (*Ts)[64] = (float(*)[64])sm;
        #pragma unroll
        for (int p = 0; p < 2; p++) {
            __syncthreads();
            if (wr == p) {
                #pragma unroll
                for (int fm = 0; fm < 4; fm++)
                    #pragma unroll
                    for (int fn = 0; fn < 4; fn++)
                        *(float4*)&Ts[wc * 64 + fn * 16 + li][fm * 16 + quad * 4] =
                            make_float4(acc[fm][fn][0], acc[fm][fn][1],
                                        acc[fm][fn][2], acc[fm][fn][3]);
            }
            __syncthreads();
            #pragma unroll
            for (int i = 0; i < 4; i++) {
                const int c = tid + 256 * i;     // 0..1023
                const int nr = c >> 3;           // 0..127
                const int mc = c & 7;            // 0..7
                const int n = n0 + nr;
                const int h = n >> 6, hd = n & 63;
                const float4 v0 = *(const float4*)&Ts[nr][mc * 8];
                const float4 v1 = *(const float4*)&Ts[nr][mc * 8 + 4];
                uint4 ov;
                ov.x = (u32)f2bf(v0.x) | ((u32)f2bf(v0.y) << 16);
                ov.y = (u32)f2bf(v0.z) | ((u32)f2bf(v0.w) << 16);
                ov.z = (u32)f2bf(v1.x) | ((u32)f2bf(v1.y) << 16);
                ov.w = (u32)f2bf(v1.z) | ((u32)f2bf(v1.w) << 16);
                *(uint4*)&outp[((size_t)(bidx * HH + h) * HDD + hd) * SS + s0 + p * 64 + mc * 8] = ov;
            }
        }
    }
}

// ---------------- MFMA flash attention (verified core; ctx out now bf16) ---------------
__global__ __launch_bounds__(256) void attn_mfma(
    const u16* __restrict__ Qb, const u16* __restrict__ Kb,
    const u16* __restrict__ Vt, u16* __restrict__ ctxb)
{
    __shared__ u16 Ks[64][72];      // [key][d]
    __shared__ u16 Vs[64][72];      // [d][key]  (from V^T)
    __shared__ u16 Ps[4][16][72];   // per-wave [q][key]
    const int tid = threadIdx.x;
    const int lane = tid & 63;
    const int w = tid >> 6;
    const int li = lane & 15;
    const int quad = lane >> 4;
    const int bh = blockIdx.y;
    const int q0 = (gridDim.x - 1 - blockIdx.x) * 64;   // heavy blocks first

    bf16x8 aQ0, aQ1;
    {
        const u16* qg = Qb + ((size_t)bh * SS + q0 + 16 * w + li) * HDD + quad * 8;
        aQ0 = *(const bf16x8*)qg;
        aQ1 = *(const bf16x8*)(qg + 32);
    }

    f32x4 O[4] = {};
    float m_r[4] = {-1e30f, -1e30f, -1e30f, -1e30f};
    float l_r[4] = {};

    const int ntiles = (q0 >> 6) + 1;
    const int krow = tid >> 3;
    const int kch = (tid & 7) * 8;

    for (int jt = 0; jt < ntiles; jt++) {
        const int j0 = jt << 6;
        const uint4 k0v = *(const uint4*)(Kb + ((size_t)bh * SS + j0 + krow) * HDD + kch);
        const uint4 k1v = *(const uint4*)(Kb + ((size_t)bh * SS + j0 + 32 + krow) * HDD + kch);
        const uint4 v0v = *(const uint4*)(Vt + ((size_t)bh * HDD + krow) * SS + j0 + kch);
        const uint4 v1v = *(const uint4*)(Vt + ((size_t)bh * HDD + 32 + krow) * SS + j0 + kch);
        __syncthreads();
        *(uint4*)&Ks[krow][kch] = k0v;
        *(uint4*)&Ks[32 + krow][kch] = k1v;
        *(uint4*)&Vs[krow][kch] = v0v;
        *(uint4*)&Vs[32 + krow][kch] = v1v;
        __syncthreads();

        f32x4 S[4];
        #pragma unroll
        for (int t = 0; t < 4; t++) {
            const bf16x8 b0 = *(const bf16x8*)&Ks[16 * t + li][quad * 8];
            const bf16x8 b1 = *(const bf16x8*)&Ks[16 * t + li][32 + quad * 8];
            f32x4 acc = {};
            acc = __builtin_amdgcn_mfma_f32_16x16x32_bf16(aQ0, b0, acc, 0, 0, 0);
            acc = __builtin_amdgcn_mfma_f32_16x16x32_bf16(aQ1, b1, acc, 0, 0, 0);
            S[t] = acc;
        }

        if (jt == ntiles - 1) {
            #pragma unroll
            for (int t = 0; t < 4; t++)
                #pragma unroll
                for (int r = 0; r < 4; r++)
                    if (16 * t + li > 16 * w + quad * 4 + r) S[t][r] = -1e30f;
        }

        float p[4][4];
        #pragma unroll
        for (int r = 0; r < 4; r++) {
            float mt = fmaxf(fmaxf(S[0][r], S[1][r]), fmaxf(S[2][r], S[3][r]));
            #pragma unroll
            for (int off = 1; off < 16; off <<= 1)
                mt = fmaxf(mt, __shfl_xor(mt, off));
            const float mnew = fmaxf(m_r[r], mt);
            const float alpha = __expf(m_r[r] - mnew);
            float ls = 0.f;
            #pragma unroll
            for (int t = 0; t < 4; t++) {
                p[r][t] = __expf(S[t][r] - mnew);
                ls += p[r][t];
            }
            #pragma unroll
            for (int off = 1; off < 16; off <<= 1)
                ls += __shfl_xor(ls, off);
            l_r[r] = l_r[r] * alpha + ls;
            m_r[r] = mnew;
            #pragma unroll
            for (int t2 = 0; t2 < 4; t2++) O[t2][r] *= alpha;
        }

        #pragma unroll
        for (int r = 0; r < 4; r++)
            #pragma unroll
            for (int t = 0; t < 4; t++)
                Ps[w][quad * 4 + r][16 * t + li] = f2bf(p[r][t]);

        const bf16x8 aP0 = *(const bf16x8*)&Ps[w][li][quad * 8];
        const bf16x8 aP1 = *(const bf16x8*)&Ps[w][li][32 + quad * 8];
        #pragma unroll
        for (int t2 = 0; t2 < 4; t2++) {
            const bf16x8 b0 = *(const bf16x8*)&Vs[16 * t2 + li][quad * 8];
            const bf16x8 b1 = *(const bf16x8*)&Vs[16 * t2 + li][32 + quad * 8];
            O[t2] = __builtin_amdgcn_mfma_f32_16x16x32_bf16(aP0, b0, O[t2], 0, 0, 0);
            O[t2] = __builtin_amdgcn_mfma_f32_16x16x32_bf16(aP1, b1, O[t2], 0, 0, 0);
        }
    }

    const int b = bh >> 4, h = bh & 15;
    #pragma unroll
    for (int r = 0; r < 4; r++) {
        const float inv = 1.f / l_r[r];
        const int row = q0 + 16 * w + quad * 4 + r;
        #pragma unroll
        for (int t2 = 0; t2 < 4; t2++)
            ctxb[((size_t)b * SS + row) * DD + h * HDD + 16 * t2 + li] = f2bf(O[t2][r] * inv);
    }
}

// ---------------- output GEMM on the verified MFMA core: ctx(bf16) @ WoT(bf16) ---------
// Direct fp32 epilogue in the verified C-layout convention (col=li, row=quad*4+r).
__global__ __launch_bounds__(256) void gemm_out_mfma(
    const u16* __restrict__ Ab, const u16* __restrict__ WoT, float* __restrict__ out)
{
    __shared__ __align__(16) u16 sm[16384];   // 32KB
    const int tid = threadIdx.x;
    const int lane = tid & 63;
    const int w = tid >> 6;
    const int li = lane & 15, quad = lane >> 4;
    const int wr = w >> 1, wc = w & 1;
    const int n0 = blockIdx.x * 128;
    const int m0 = blockIdx.y * 128;

    const int srow = tid >> 2;          // 0..63
    const int scol = (tid & 3) * 8;     // 0,8,16,24

    uint4 ra[2], rb[2], na[2], nb[2];
    #pragma unroll
    for (int rr = 0; rr < 2; rr++) {
        ra[rr] = *(const uint4*)(Ab  + (size_t)(m0 + rr * 64 + srow) * DD + scol);
        rb[rr] = *(const uint4*)(WoT + (size_t)(n0 + rr * 64 + srow) * DD + scol);
    }

    f32x4 acc[4][4] = {};
    for (int t = 0; t < 32; t++) {
        u16* base = sm + (t & 1) * 8192;
        #pragma unroll
        for (int rr = 0; rr < 2; rr++) {
            *(uint4*)&base[(rr * 64 + srow) * 32 + scol] = ra[rr];
            *(uint4*)&base[4096 + (rr * 64 + srow) * 32 + scol] = rb[rr];
        }
        if (t < 31) {
            const int k1 = (t + 1) * 32;
            #pragma unroll
            for (int rr = 0; rr < 2; rr++) {
                na[rr] = *(const uint4*)(Ab  + (size_t)(m0 + rr * 64 + srow) * DD + k1 + scol);
                nb[rr] = *(const uint4*)(WoT + (size_t)(n0 + rr * 64 + srow) * DD + k1 + scol);
            }
        }
        __syncthreads();
        bf16x8 a[4], b[4];
        #pragma unroll
        for (int f = 0; f < 4; f++) {
            a[f] = *(const bf16x8*)(base + (wr * 64 + f * 16 + li) * 32 + quad * 8);
            b[f] = *(const bf16x8*)(base + 4096 + (wc * 64 + f * 16 + li) * 32 + quad * 8);
        }
        #pragma unroll
        for (int fm = 0; fm < 4; fm++)
            #pragma unroll
            for (int fn = 0; fn < 4; fn++)
                acc[fm][fn] = __builtin_amdgcn_mfma_f32_16x16x32_bf16(
                    a[fm], b[fn], acc[fm][fn], 0, 0, 0);
        if (t < 31) {
            #pragma unroll
            for (int rr = 0; rr < 2; rr++) { ra[rr] = na[rr]; rb[rr] = nb[rr]; }
        }
        __syncthreads();
    }

    #pragma unroll
    for (int fm = 0; fm < 4; fm++)
        #pragma unroll
        for (int r = 0; r < 4; r++) {
            const size_t mg = (size_t)(m0 + wr * 64 + fm * 16 + quad * 4 + r) * DD;
            #pragma unroll
            for (int fn = 0; fn < 4; fn++)
                out[mg + n0 + wc * 64 + fn * 16 + li] = acc[fm][fn][r];
        }
}

extern "C" void kernel_launch(void* const* d_in, const int* in_sizes, int n_in,
                              void* d_out, int out_size, void* d_ws, size_t ws_size,
                              hipStream_t stream) {
    const float* x  = (const float*)d_in[0];
    const float* Wq = (const float*)d_in[1];
    const float* Wk = (const float*)d_in[2];
    const float* Wv = (const float*)d_in[3];
    const float* Wo = (const float*)d_in[4];
    float* out = (float*)d_out;

    u16* ws16 = (u16*)d_ws;
    const size_t E = 4194304;                 // B*H*S*HD elems
    const size_t M = 1048576;                 // D*D elems
    u16* QKVb = ws16;                         // [0,3E): Qb|Kb|Vt contiguous
    u16* Qb   = QKVb;
    u16* Kb   = QKVb + E;
    u16* Vt   = QKVb + 2 * E;
    u16* Xb   = ws16 + 3 * E;                 // [3E,4E), dead after QKV GEMM
    u16* ctxb = Xb;                           // reuse after QKV
    u16* WTall = ws16 + 4 * E;                // [4E,4E+3M): WqT|WkT|WvT contiguous
    u16* WoT  = WTall + 3 * M;                // [4E+3M, 4E+4M)  => 40 MiB total

    hipLaunchKernelGGL(cvt_x, dim3(1024), dim3(256), 0, stream, x, Xb);
    hipLaunchKernelGGL(trans_w, dim3(32, 32), dim3(256), 0, stream, Wq, WTall);
    hipLaunchKernelGGL(trans_w, dim3(32, 32), dim3(256), 0, stream, Wk, WTall + M);
    hipLaunchKernelGGL(trans_w, dim3(32, 32), dim3(256), 0, stream, Wv, WTall + 2 * M);
    hipLaunchKernelGGL(trans_w, dim3(32, 32), dim3(256), 0, stream, Wo, WoT);
    hipLaunchKernelGGL(gemm_qkv_all, dim3(24, 32), dim3(256), 0, stream, Xb, WTall, QKVb);
    hipLaunchKernelGGL(attn_mfma, dim3(SS / 64, BB * HH), dim3(256), 0, stream,
                       Qb, Kb, Vt, ctxb);
    hipLaunchKernelGGL(gemm_out_mfma, dim3(8, 32), dim3(256), 0, stream, ctxb, WoT, out);
}